// Round 5
// baseline (377.897 us; speedup 1.0000x reference)
//
#include <hip/hip_runtime.h>
#include <hip/hip_bf16.h>
#include <math.h>

// Problem constants
constexpr int B_ = 8, C_ = 256, H_ = 64, W_ = 64;
constexpr int N_ = H_ * W_;          // 4096
constexpr int NH_ = 8;
constexpr int CM_ = 2048;
constexpr int M_ = B_ * N_;          // 32768
constexpr float EPS_ = 1e-5f;

typedef __bf16 bf16_t;
typedef bf16_t bf16x8 __attribute__((ext_vector_type(8)));
typedef float f32x4 __attribute__((ext_vector_type(4)));
typedef float f32x16 __attribute__((ext_vector_type(16)));
typedef unsigned int u32x4 __attribute__((ext_vector_type(4)));

__device__ inline bf16_t f2b(float f) {
    __hip_bfloat16 h = __float2bfloat16(f);
    return *reinterpret_cast<bf16_t*>(&h);
}
__device__ inline float b2f(bf16_t b) {
    unsigned short u = *reinterpret_cast<unsigned short*>(&b);
    unsigned int x = (unsigned int)u << 16;
    return *reinterpret_cast<float*>(&x);
}
__device__ inline unsigned pk2(float lo, float hi) {
    bf16_t l = f2b(lo), h = f2b(hi);
    unsigned short ls = *reinterpret_cast<unsigned short*>(&l);
    unsigned short hs = *reinterpret_cast<unsigned short*>(&h);
    return ((unsigned)hs << 16) | (unsigned)ls;
}
__device__ inline float gelu_ap(float y) {
    float u = y * (0.7978845608f + 0.0356774081f * y * y);
    float e = __expf(2.0f * u);
    return y - y * __builtin_amdgcn_rcpf(e + 1.0f);
}

#define GLOAD_LDS16(gptr, lptr)                                                     \
    __builtin_amdgcn_global_load_lds(                                               \
        (const __attribute__((address_space(1))) void*)(gptr),                      \
        (__attribute__((address_space(3))) void*)(lptr), 16, 0, 0)

// ---------------------------------------------------------------------------
// Transpose [B,C,N] -> [B,N,C] (bf16 out). MODE 0: f32 in; MODE 1: bf16 in.
template <int MODE>
__global__ void transpose_cast(const void* __restrict__ in_, bf16_t* __restrict__ outb) {
    __shared__ float tile[32][33];
    int b  = blockIdx.z;
    int n0 = blockIdx.x * 32;
    int c0 = blockIdx.y * 32;
    int tx = threadIdx.x, ty = threadIdx.y;
#pragma unroll
    for (int i = ty; i < 32; i += 8) {
        size_t off = (size_t)b * C_ * N_ + (size_t)(c0 + i) * N_ + n0 + tx;
        tile[i][tx] = (MODE == 0) ? ((const float*)in_)[off] : b2f(((const bf16_t*)in_)[off]);
    }
    __syncthreads();
#pragma unroll
    for (int i = ty; i < 32; i += 8) {
        size_t off = (size_t)b * N_ * C_ + (size_t)(n0 + i) * C_ + c0 + tx;
        outb[off] = f2b(tile[tx][i]);
    }
}

// ---------------------------------------------------------------------------
// Weight cast + transpose: W [K,N] f32 -> Wt [N,K] bf16
__global__ void wcastT(const float* __restrict__ W, bf16_t* __restrict__ Wt,
                       int K, int N) {
    __shared__ float tile[32][33];
    int k0 = blockIdx.y * 32, n0 = blockIdx.x * 32;
    int tx = threadIdx.x, ty = threadIdx.y;
#pragma unroll
    for (int i = ty; i < 32; i += 8)
        tile[i][tx] = W[(size_t)(k0 + i) * N + n0 + tx];
    __syncthreads();
#pragma unroll
    for (int i = ty; i < 32; i += 8)
        Wt[(size_t)(n0 + i) * K + k0 + tx] = f2b(tile[tx][i]);
}

// ---------------------------------------------------------------------------
// bf16 MFMA GEMM (16x16x32): C = A[M,K] @ Bt[N,K]^T + bias, fused epilogues.
// EPI 1: z=b2f(tres_b)+acc+bias; repbn1 -> Cb (bf16)
// EPI 4: acc+bias -> Cb (bf16)
template <int EPI>
__global__ __launch_bounds__(256)
void gemm_bf16(const bf16_t* __restrict__ A, const bf16_t* __restrict__ Bt,
               const float* __restrict__ bias,
               float* __restrict__ Cf, bf16_t* __restrict__ Cb,
               int M, int N, int K,
               const bf16_t* __restrict__ tres_b,
               const float* __restrict__ g, const float* __restrict__ bb,
               const float* __restrict__ mm, const float* __restrict__ vv,
               const float* __restrict__ alpha, int row_off) {
    __shared__ bf16x8 ldsv[2048];          // 32 KB
    char* lds = (char*)ldsv;

    int tid  = threadIdx.x;
    int lane = tid & 63;
    int w    = tid >> 6;
    int wm   = w >> 1, wn = w & 1;
    int brow = blockIdx.y * 128, bcol = blockIdx.x * 128;
    int rowl = lane & 15, kq = lane >> 4;

    f32x4 acc[4][4] = {};

    for (int k0 = 0; k0 < K; k0 += 64) {
#pragma unroll
        for (int j = 0; j < 4; ++j) {
            int jj = w * 4 + j;
            int msub = jj >> 1, kh = jj & 1;
            const bf16_t* ga = A + ((size_t)(brow + msub * 16 + rowl) * K + k0 + kh * 32 + kq * 8);
            GLOAD_LDS16(ga, lds + jj * 1024);
            const bf16_t* gb = Bt + ((size_t)(bcol + msub * 16 + rowl) * K + k0 + kh * 32 + kq * 8);
            GLOAD_LDS16(gb, lds + 16384 + jj * 1024);
        }
        __syncthreads();
#pragma unroll
        for (int ks = 0; ks < 2; ++ks) {
            bf16x8 af[4], bfr[4];
#pragma unroll
            for (int m = 0; m < 4; ++m) af[m] = ldsv[((wm * 4 + m) * 2 + ks) * 64 + lane];
#pragma unroll
            for (int n = 0; n < 4; ++n) bfr[n] = ldsv[1024 + ((wn * 4 + n) * 2 + ks) * 64 + lane];
#pragma unroll
            for (int m = 0; m < 4; ++m)
#pragma unroll
                for (int n = 0; n < 4; ++n)
                    acc[m][n] = __builtin_amdgcn_mfma_f32_16x16x32_bf16(af[m], bfr[n], acc[m][n], 0, 0, 0);
        }
        __syncthreads();
    }

    float alpha_v = (EPI == 1) ? alpha[0] : 0.f;
#pragma unroll
    for (int m = 0; m < 4; ++m) {
#pragma unroll
        for (int n = 0; n < 4; ++n) {
            int col = bcol + wn * 64 + n * 16 + (lane & 15);
            float bv = bias[col];
#pragma unroll
            for (int r = 0; r < 4; ++r) {
                int row = brow + wm * 64 + m * 16 + (lane >> 4) * 4 + r;
                float y = acc[m][n][r] + bv;
                if (EPI == 4) {
                    Cb[(size_t)row * N + col] = f2b(y);
                } else {  // EPI 1
                    float z = b2f(tres_b[(size_t)row * N + col]) + y;
                    float rr = (z - mm[col]) * rsqrtf(vv[col] + EPS_) * g[col] + bb[col] + alpha_v * z;
                    Cb[(size_t)row * N + col] = f2b(rr);
                }
            }
        }
    }
}

// ---------------------------------------------------------------------------
// Fused FFN: out = repbn2(t + gelu(t@W1+b1)@W2 + b2), transposed to [B,C,N].
// 32x32x16 MFMA. Grid M/128 blocks x 4 waves; wave owns 32 rows x all 256 cols.
// Hidden in 64 chunks of 32. GEMM1 operand-swapped -> h^T frags stay in regs;
// half-wave shfl_xor assembles GEMM2 A-frags. W1/W2 chunks double-buffered LDS.
__global__ __launch_bounds__(256)
void ffn_fused(const bf16_t* __restrict__ Aact, const bf16_t* __restrict__ W1t,
               const bf16_t* __restrict__ W2t,
               const float* __restrict__ bfc1, const float* __restrict__ bfc2,
               const float* __restrict__ g, const float* __restrict__ bb,
               const float* __restrict__ mm, const float* __restrict__ vv,
               const float* __restrict__ alpha, float* __restrict__ out) {
    __shared__ bf16x8 ldsv[8192];          // 128 KB
    char* lds = (char*)ldsv;
    // units of bf16x8 (16 B): A region [0,4096); W1 bufs 4096+p*1024; W2 6144+p*1024
    const int tid = threadIdx.x;
    const int lane = tid & 63;
    const int w = tid >> 6;
    const int l31 = lane & 31;
    const int h = lane >> 5;
    const int brow = blockIdx.x * 128;

    // ---- prologue: stage A tile (128x256) + W chunk 0 into buf 0
    {
        const bf16_t* ga = Aact + (size_t)(brow + 32 * w + l31) * 256 + h * 8;
#pragma unroll
        for (int kc = 0; kc < 16; ++kc)
            GLOAD_LDS16(ga + kc * 16, lds + (w * 16 + kc) * 1024);
        const bf16_t* g1 = W1t + (size_t)l31 * 256 + h * 8;   // chunk 0
#pragma unroll
        for (int i = 0; i < 4; ++i) {
            int kc = w * 4 + i;
            GLOAD_LDS16(g1 + kc * 16, lds + 65536 + kc * 1024);
        }
#pragma unroll
        for (int i = 0; i < 4; ++i) {
            int fid = w * 4 + i, cb = fid >> 1, ks = fid & 1;
            const bf16_t* g2 = W2t + (size_t)(32 * cb + l31) * 2048 + ks * 16 + h * 8;
            GLOAD_LDS16(g2, lds + 98304 + fid * 1024);
        }
    }
    __syncthreads();

    // ---- A fragments -> registers (wave's own m-block)
    bf16x8 areg[16];
#pragma unroll
    for (int kc = 0; kc < 16; ++kc) areg[kc] = ldsv[(w * 16 + kc) * 64 + lane];

    f32x16 acc2[8];
#pragma unroll
    for (int cb = 0; cb < 8; ++cb) acc2[cb] = (f32x16)0.f;

    const float* bp1 = bfc1 + 4 * h;

    for (int c = 0; c < 64; ++c) {
        int p = c & 1;
        // stage next chunk into buf p^1
        if (c + 1 < 64) {
            int cn = c + 1, pn = p ^ 1;
            const bf16_t* g1 = W1t + (size_t)(32 * cn + l31) * 256 + h * 8;
#pragma unroll
            for (int i = 0; i < 4; ++i) {
                int kc = w * 4 + i;
                GLOAD_LDS16(g1 + kc * 16, lds + 65536 + pn * 16384 + kc * 1024);
            }
#pragma unroll
            for (int i = 0; i < 4; ++i) {
                int fid = w * 4 + i, cb = fid >> 1, ks = fid & 1;
                const bf16_t* g2 = W2t + (size_t)(32 * cb + l31) * 2048 + 32 * cn + ks * 16 + h * 8;
                GLOAD_LDS16(g2, lds + 98304 + pn * 16384 + fid * 1024);
            }
        }

        // ---- GEMM1 (swapped): acc1 = h^T frag; init with fc1 bias
        f32x16 acc1;
#pragma unroll
        for (int r = 0; r < 16; ++r)
            acc1[r] = bp1[32 * c + (r & 3) + 8 * (r >> 2)];
#pragma unroll
        for (int kc = 0; kc < 16; ++kc) {
            bf16x8 w1f = ldsv[4096 + p * 1024 + kc * 64 + lane];
            acc1 = __builtin_amdgcn_mfma_f32_32x32x16_bf16(w1f, areg[kc], acc1, 0, 0, 0);
        }

        // ---- GELU + pack + half-wave exchange -> GEMM2 A-frags
        unsigned words[8];
#pragma unroll
        for (int t = 0; t < 4; ++t)
#pragma unroll
            for (int s = 0; s < 2; ++s)
                words[t * 2 + s] = pk2(gelu_ap(acc1[4 * t + 2 * s]),
                                       gelu_ap(acc1[4 * t + 2 * s + 1]));
        bf16x8 hf[2];
#pragma unroll
        for (int ks = 0; ks < 2; ++ks) {
            unsigned u0 = words[(2 * ks) * 2 + 0], u1 = words[(2 * ks) * 2 + 1];
            unsigned v0 = words[(2 * ks + 1) * 2 + 0], v1 = words[(2 * ks + 1) * 2 + 1];
            unsigned su0 = __shfl_xor(u0, 32);
            unsigned su1 = __shfl_xor(u1, 32);
            unsigned sv0 = __shfl_xor(v0, 32);
            unsigned sv1 = __shfl_xor(v1, 32);
            u32x4 t4;
            t4[0] = h ? sv0 : u0;
            t4[1] = h ? sv1 : u1;
            t4[2] = h ? v0 : su0;
            t4[3] = h ? v1 : su1;
            hf[ks] = __builtin_bit_cast(bf16x8, t4);
        }

        // ---- GEMM2: acc2[cb] += h @ W2chunk
#pragma unroll
        for (int cb = 0; cb < 8; ++cb) {
            bf16x8 w2f0 = ldsv[6144 + p * 1024 + (cb * 2 + 0) * 64 + lane];
            acc2[cb] = __builtin_amdgcn_mfma_f32_32x32x16_bf16(hf[0], w2f0, acc2[cb], 0, 0, 0);
            bf16x8 w2f1 = ldsv[6144 + p * 1024 + (cb * 2 + 1) * 64 + lane];
            acc2[cb] = __builtin_amdgcn_mfma_f32_32x32x16_bf16(hf[1], w2f1, acc2[cb], 0, 0, 0);
        }
        __syncthreads();
    }

    // ---- epilogue: repbn2 + transpose to [B,C,N] (f32 out)
    float alpha_v = alpha[0];
#pragma unroll
    for (int cb = 0; cb < 8; ++cb) {
        int cc = cb * 32 + l31;
        float bv = bfc2[cc];
        float rs = rsqrtf(vv[cc] + EPS_) * g[cc];
        float bbv = bb[cc], mv = mm[cc];
#pragma unroll
        for (int r = 0; r < 16; ++r) {
            int m = brow + 32 * w + (r & 3) + 8 * (r >> 2) + 4 * h;
            float z = b2f(Aact[(size_t)m * 256 + cc]) + acc2[cb][r] + bv;
            float rr = (z - mv) * rs + bbv + alpha_v * z;
            int bi = m >> 12, ni = m & (N_ - 1);
            out[((size_t)bi * C_ + cc) * N_ + ni] = rr;
        }
    }
}

// ---------------------------------------------------------------------------
// ctx partials: ctxp[seg][b*NH+h][d][e] = sum_{n in seg} relu(k[n,d]) * v[n,e]
__global__ void ctx_partial(const bf16_t* __restrict__ qkv, float* __restrict__ ctxp) {
    __shared__ float kb[64][40];
    __shared__ float vb[64][40];
    int seg = blockIdx.x;
    int bh  = blockIdx.y;
    int b = bh >> 3, h = bh & 7;
    int tid = threadIdx.x;
    int d  = tid >> 3;
    int e0 = (tid & 7) * 4;
    int lrow = tid >> 2, lcol = (tid & 3) * 8;
    float acc[4] = {0.f, 0.f, 0.f, 0.f};
    const size_t base = (size_t)b * N_ * 768 + h * 32;
    for (int n0 = seg * 512; n0 < seg * 512 + 512; n0 += 64) {
        size_t ra = base + (size_t)(n0 + lrow) * 768 + lcol;
        bf16x8 kv8 = *(const bf16x8*)(qkv + ra + 256);
        bf16x8 vv8 = *(const bf16x8*)(qkv + ra + 512);
#pragma unroll
        for (int j = 0; j < 8; ++j) {
            kb[lrow][lcol + j] = b2f(kv8[j]);
            vb[lrow][lcol + j] = b2f(vv8[j]);
        }
        __syncthreads();
#pragma unroll
        for (int nl = 0; nl < 64; ++nl) {
            float kv = fmaxf(kb[nl][d], 0.f);
#pragma unroll
            for (int j = 0; j < 4; ++j)
                acc[j] = fmaf(kv, vb[nl][e0 + j], acc[j]);
        }
        __syncthreads();
    }
    float* o = ctxp + ((size_t)seg * 64 + bh) * 1024 + d * 32 + e0;
#pragma unroll
    for (int j = 0; j < 4; ++j) o[j] = acc[j];
}

__global__ void ctx_reduce(const float* __restrict__ ctxp, float* __restrict__ ctx) {
    int idx = blockIdx.x * 256 + threadIdx.x;
    float s = 0.f;
#pragma unroll
    for (int seg = 0; seg < 8; ++seg) s += ctxp[(size_t)seg * 65536 + idx];
    ctx[idx] = s;
}

// ---------------------------------------------------------------------------
__global__ void attn_out(const bf16_t* __restrict__ qkv, const float* __restrict__ ctx,
                         bf16_t* __restrict__ img) {
    __shared__ float qb[64][33];
    __shared__ float cs[32][32];
    int n0 = blockIdx.x * 64;
    int bh = blockIdx.y;
    int b = bh >> 3, h = bh & 7;
    int tid = threadIdx.x;
    const float scale = 0.17677669529663687f;
    {
        float4 vv = ((const float4*)(ctx + (size_t)bh * 1024))[tid];
        ((float4*)&cs[0][0])[tid] = vv;
    }
    const size_t base = (size_t)b * N_ * 768 + h * 32;
    int lrow = tid >> 2, lcol = (tid & 3) * 8;
    {
        bf16x8 q8 = *(const bf16x8*)(qkv + base + (size_t)(n0 + lrow) * 768 + lcol);
#pragma unroll
        for (int j = 0; j < 8; ++j)
            qb[lrow][lcol + j] = fmaxf(b2f(q8[j]), 0.f) * scale;
    }
    __syncthreads();
    int nl = tid & 63, ebase = tid >> 6;
    bf16_t* outp = img + ((size_t)b * C_ + h * 32) * N_ + n0 + nl;
#pragma unroll
    for (int p = 0; p < 8; ++p) {
        int e = ebase + p * 4;
        float s = 0.f;
#pragma unroll
        for (int dd = 0; dd < 32; ++dd)
            s = fmaf(qb[nl][dd], cs[dd][e], s);
        outp[(size_t)e * N_] = f2b(s);
    }
}

// ---------------------------------------------------------------------------
__global__ __launch_bounds__(256)
void dwconv3x3(const bf16_t* __restrict__ img, const float* __restrict__ w,
               const float* __restrict__ bias, bf16_t* __restrict__ out) {
    __shared__ float sp[64][65];
    int bc = blockIdx.x;
    int c  = bc & 255;
    int tid = threadIdx.x;
    const bf16_t* ip = img + (size_t)bc * N_;
#pragma unroll
    for (int l = 0; l < 2; ++l) {
        int flat = (tid + l * 256) * 8;
        int row = flat >> 6, col = flat & 63;
        bf16x8 v8 = *(const bf16x8*)(ip + flat);
#pragma unroll
        for (int j = 0; j < 8; ++j) sp[row][col + j] = b2f(v8[j]);
    }
    float wv[9];
#pragma unroll
    for (int j = 0; j < 9; ++j) wv[j] = w[c * 9 + j];
    float bv = bias[c];
    __syncthreads();

    int y = tid >> 2, x0 = (tid & 3) * 16;
    float o[16];
#pragma unroll
    for (int i = 0; i < 16; ++i) o[i] = bv;
#pragma unroll
    for (int dy = -1; dy <= 1; ++dy) {
        int yy = y + dy;
        if (yy < 0 || yy > 63) continue;
#pragma unroll
        for (int dx = -1; dx <= 1; ++dx) {
            float wgt = wv[(dy + 1) * 3 + dx + 1];
#pragma unroll
            for (int i = 0; i < 16; ++i) {
                int xx = x0 + i + dx;
                float val = (xx < 0 || xx > 63) ? 0.f : sp[yy][xx];
                o[i] = fmaf(wgt, val, o[i]);
            }
        }
    }
    bf16_t ob[16];
#pragma unroll
    for (int i = 0; i < 16; ++i) ob[i] = f2b(o[i]);
    *(bf16x8*)(out + (size_t)bc * N_ + y * 64 + x0)     = *(bf16x8*)&ob[0];
    *(bf16x8*)(out + (size_t)bc * N_ + y * 64 + x0 + 8) = *(bf16x8*)&ob[8];
}

// ---------------------------------------------------------------------------
extern "C" void kernel_launch(void* const* d_in, const int* in_sizes, int n_in,
                              void* d_out, int out_size, void* d_ws, size_t ws_size,
                              hipStream_t stream) {
    const float* x     = (const float*)d_in[0];
    const float* Wqkv  = (const float*)d_in[1];
    const float* bqkv  = (const float*)d_in[2];
    const float* dw_w  = (const float*)d_in[3];
    const float* dw_b  = (const float*)d_in[4];
    const float* Wproj = (const float*)d_in[5];
    const float* bproj = (const float*)d_in[6];
    const float* bn1_g = (const float*)d_in[7];
    const float* bn1_b = (const float*)d_in[8];
    const float* bn1_m = (const float*)d_in[9];
    const float* bn1_v = (const float*)d_in[10];
    const float* alpha1= (const float*)d_in[11];
    const float* Wfc1  = (const float*)d_in[12];
    const float* bfc1  = (const float*)d_in[13];
    const float* Wfc2  = (const float*)d_in[14];
    const float* bfc2  = (const float*)d_in[15];
    const float* bn2_g = (const float*)d_in[16];
    const float* bn2_b = (const float*)d_in[17];
    const float* bn2_m = (const float*)d_in[18];
    const float* bn2_v = (const float*)d_in[19];
    const float* alpha2= (const float*)d_in[20];
    float* out = (float*)d_out;

    char* ws = (char*)d_ws;
    // Workspace layout (bytes), peak ~139 MB <= proven 170 MB:
    //   t_b2    @ 0            16,777,216  bf16 [B,N,C]
    //   WqkvT   @ 16,777,216      393,216
    //   WprojT  @ 17,170,432      131,072
    //   Wfc1T   @ 17,301,504    1,048,576
    //   Wfc2T   @ 18,350,080    1,048,576
    //   ctxp    @ 19,398,656    2,097,152
    //   ctx     @ 21,495,808      262,144
    //   t_b     @ 21,757,952   16,777,216  bf16 [B,N,C]
    //   qkv_b   @ 38,535,168   50,331,648  bf16 [B,N,768]
    //   img_b   @ 88,866,816   16,777,216  bf16 [B,C,N]
    //   conv_b  @ 105,644,032  16,777,216  bf16 [B,C,N]
    //   convT_b @ 122,421,248  16,777,216  bf16 [B,N,C]
    bf16_t* t_b2    = (bf16_t*)(ws);
    bf16_t* WqkvT   = (bf16_t*)(ws + 16777216);
    bf16_t* WprojT  = (bf16_t*)(ws + 17170432);
    bf16_t* Wfc1T   = (bf16_t*)(ws + 17301504);
    bf16_t* Wfc2T   = (bf16_t*)(ws + 18350080);
    float*  ctxp    = (float*)(ws + 19398656);
    float*  ctx     = (float*)(ws + 21495808);
    bf16_t* t_b     = (bf16_t*)(ws + 21757952);
    bf16_t* qkv_b   = (bf16_t*)(ws + 38535168);
    bf16_t* img_b   = (bf16_t*)(ws + 88866816);
    bf16_t* conv_b  = (bf16_t*)(ws + 105644032);
    bf16_t* convT_b = (bf16_t*)(ws + 122421248);

    // ph1: x -> t_b (bf16); weight casts
    transpose_cast<0><<<dim3(N_ / 32, C_ / 32, B_), dim3(32, 8), 0, stream>>>(x, t_b);
    wcastT<<<dim3(768 / 32, C_ / 32), dim3(32, 8), 0, stream>>>(Wqkv, WqkvT, C_, 768);
    wcastT<<<dim3(C_ / 32, C_ / 32), dim3(32, 8), 0, stream>>>(Wproj, WprojT, C_, C_);
    wcastT<<<dim3(CM_ / 32, C_ / 32), dim3(32, 8), 0, stream>>>(Wfc1, Wfc1T, C_, CM_);
    wcastT<<<dim3(C_ / 32, CM_ / 32), dim3(32, 8), 0, stream>>>(Wfc2, Wfc2T, CM_, C_);

    // ph2: qkv_b = bf16(t @ Wqkv + bqkv)
    gemm_bf16<4><<<dim3(768 / 128, M_ / 128), 256, 0, stream>>>(
        t_b, WqkvT, bqkv, nullptr, qkv_b, M_, 768, C_,
        nullptr, nullptr, nullptr, nullptr, nullptr, nullptr, 0);

    // ph3: ctx = relu(k)^T v
    ctx_partial<<<dim3(8, B_ * NH_), 256, 0, stream>>>(qkv_b, ctxp);
    ctx_reduce<<<256, 256, 0, stream>>>(ctxp, ctx);

    // ph4: img_b = (relu(q)*scale) @ ctx   [B,C,N] bf16
    attn_out<<<dim3(N_ / 64, B_ * NH_), 256, 0, stream>>>(qkv_b, ctx, img_b);

    // ph5: depthwise conv (bf16 -> bf16)
    dwconv3x3<<<B_ * C_, 256, 0, stream>>>(img_b, dw_w, dw_b, conv_b);

    // ph6: conv_b -> convT_b (bf16 [B,N,C])
    transpose_cast<1><<<dim3(N_ / 32, C_ / 32, B_), dim3(32, 8), 0, stream>>>(conv_b, convT_b);

    // ph7: t_b2 = repbn1(t_b + convT @ Wproj + bproj)   (bf16)
    gemm_bf16<1><<<dim3(C_ / 128, M_ / 128), 256, 0, stream>>>(
        convT_b, WprojT, bproj, nullptr, t_b2, M_, C_, C_,
        t_b, bn1_g, bn1_b, bn1_m, bn1_v, alpha1, 0);

    // ph8: fused FFN (fc1 + gelu + fc2 + repbn2 + transpose-out)
    ffn_fused<<<M_ / 128, 256, 0, stream>>>(
        t_b2, Wfc1T, Wfc2T, bfc1, bfc2,
        bn2_g, bn2_b, bn2_m, bn2_v, alpha2, out);
}